// Round 1
// baseline (1696.636 us; speedup 1.0000x reference)
//
#include <hip/hip_runtime.h>
#include <hip/hip_bf16.h>

#define N_NODES 50000
#define N_EDGES 800000
#define FEAT 128
#define CH 4
#define NF (N_NODES * FEAT)   // floats per channel of agg

// ---------------------------------------------------------------------------
// Pack weight [F][O][C] -> Wt [C][O][F] so GEMM1 inner loop reads contiguous
// float4 along F.
// ---------------------------------------------------------------------------
__global__ void pack_w_kernel(const float* __restrict__ w, float* __restrict__ wt) {
    int idx = blockIdx.x * blockDim.x + threadIdx.x;  // over 128*128*4
    if (idx >= FEAT * FEAT * CH) return;
    int c = idx & 3;
    int o = (idx >> 2) & 127;
    int f = idx >> 9;
    wt[c * (FEAT * FEAT) + o * FEAT + f] = w[idx];
}

// ---------------------------------------------------------------------------
// Edge scatter: agg[c][dst][f] += x[src][f] * ew[e][c]
// 128 threads per edge (one per feature), 2 edges per 256-thread block.
// ---------------------------------------------------------------------------
__global__ __launch_bounds__(256) void scatter_kernel(
        const float* __restrict__ node_state,
        const float* __restrict__ ew,
        const int* __restrict__ src,
        const int* __restrict__ dst,
        float* __restrict__ agg) {
    int e = blockIdx.x * 2 + (threadIdx.x >> 7);
    if (e >= N_EDGES) return;
    int f = threadIdx.x & 127;
    int s = src[e];
    int d = dst[e];
    float x = node_state[s * FEAT + f];
    float4 w = ((const float4*)ew)[e];
    int base = d * FEAT + f;
    atomicAdd(&agg[0 * NF + base], x * w.x);
    atomicAdd(&agg[1 * NF + base], x * w.y);
    atomicAdd(&agg[2 * NF + base], x * w.z);
    atomicAdd(&agg[3 * NF + base], x * w.w);
}

// ---------------------------------------------------------------------------
// GEMM1: h[n][o] = sum_c relu( sum_f agg[c][n][f] * Wt[c][o][f] + bias[o][c] )
// Block: 256 threads, tile = 64 rows x 128 outputs. A-tile in LDS.
// Thread: 8 rows (rg*8..rg*8+7) x 4 outputs (o4..o4+3).
// ---------------------------------------------------------------------------
__global__ __launch_bounds__(256) void gemm1_kernel(
        const float* __restrict__ agg,
        const float* __restrict__ wt,
        const float* __restrict__ bias,
        float* __restrict__ h) {
    __shared__ float Atile[64 * FEAT];  // 32 KB
    const int row0 = blockIdx.x * 64;
    const int t = threadIdx.x;
    const int o4 = (t & 31) * 4;
    const int rg = t >> 5;  // 0..7

    float hacc[8][4];
    #pragma unroll
    for (int r = 0; r < 8; ++r)
        #pragma unroll
        for (int i = 0; i < 4; ++i) hacc[r][i] = 0.f;

    for (int c = 0; c < CH; ++c) {
        __syncthreads();  // protect previous channel's Atile reads
        const float* aggc = agg + c * NF;
        #pragma unroll
        for (int k = 0; k < 8; ++k) {
            int flat = k * 1024 + t * 4;
            int r = flat >> 7;
            int col = flat & 127;
            int gr = row0 + r;
            float4 v = make_float4(0.f, 0.f, 0.f, 0.f);
            if (gr < N_NODES) v = *(const float4*)&aggc[gr * FEAT + col];
            *(float4*)&Atile[r * FEAT + col] = v;
        }
        __syncthreads();

        float acc[8][4];
        #pragma unroll
        for (int r = 0; r < 8; ++r)
            #pragma unroll
            for (int i = 0; i < 4; ++i) acc[r][i] = 0.f;

        const float* wc = wt + c * (FEAT * FEAT);
        for (int fs = 0; fs < FEAT / 4; ++fs) {
            float4 w0 = *(const float4*)&wc[(o4 + 0) * FEAT + fs * 4];
            float4 w1 = *(const float4*)&wc[(o4 + 1) * FEAT + fs * 4];
            float4 w2 = *(const float4*)&wc[(o4 + 2) * FEAT + fs * 4];
            float4 w3 = *(const float4*)&wc[(o4 + 3) * FEAT + fs * 4];
            #pragma unroll
            for (int r = 0; r < 8; ++r) {
                float4 a = *(const float4*)&Atile[(rg * 8 + r) * FEAT + fs * 4];
                acc[r][0] += a.x * w0.x + a.y * w0.y + a.z * w0.z + a.w * w0.w;
                acc[r][1] += a.x * w1.x + a.y * w1.y + a.z * w1.z + a.w * w1.w;
                acc[r][2] += a.x * w2.x + a.y * w2.y + a.z * w2.z + a.w * w2.w;
                acc[r][3] += a.x * w3.x + a.y * w3.y + a.z * w3.z + a.w * w3.w;
            }
        }
        #pragma unroll
        for (int i = 0; i < 4; ++i) {
            float b = bias[(o4 + i) * CH + c];
            #pragma unroll
            for (int r = 0; r < 8; ++r)
                hacc[r][i] += fmaxf(acc[r][i] + b, 0.f);
        }
    }

    #pragma unroll
    for (int r = 0; r < 8; ++r) {
        int gr = row0 + rg * 8 + r;
        if (gr < N_NODES) {
            float4 v = make_float4(hacc[r][0], hacc[r][1], hacc[r][2], hacc[r][3]);
            *(float4*)&h[gr * FEAT + o4] = v;
        }
    }
}

// ---------------------------------------------------------------------------
// GEMM2: out[n][j] = sum_o h[n][o] * final_w[j][o] + final_b[j]
// (final_w is [j][o], row-contiguous in o = the K dim -> float4 loads)
// ---------------------------------------------------------------------------
__global__ __launch_bounds__(256) void gemm2_kernel(
        const float* __restrict__ h,
        const float* __restrict__ fw,
        const float* __restrict__ fb,
        float* __restrict__ out) {
    __shared__ float Atile[64 * FEAT];
    const int row0 = blockIdx.x * 64;
    const int t = threadIdx.x;
    const int j4 = (t & 31) * 4;
    const int rg = t >> 5;

    #pragma unroll
    for (int k = 0; k < 8; ++k) {
        int flat = k * 1024 + t * 4;
        int r = flat >> 7;
        int col = flat & 127;
        int gr = row0 + r;
        float4 v = make_float4(0.f, 0.f, 0.f, 0.f);
        if (gr < N_NODES) v = *(const float4*)&h[gr * FEAT + col];
        *(float4*)&Atile[r * FEAT + col] = v;
    }
    __syncthreads();

    float acc[8][4];
    #pragma unroll
    for (int r = 0; r < 8; ++r)
        #pragma unroll
        for (int i = 0; i < 4; ++i) acc[r][i] = 0.f;

    for (int os = 0; os < FEAT / 4; ++os) {
        float4 w0 = *(const float4*)&fw[(j4 + 0) * FEAT + os * 4];
        float4 w1 = *(const float4*)&fw[(j4 + 1) * FEAT + os * 4];
        float4 w2 = *(const float4*)&fw[(j4 + 2) * FEAT + os * 4];
        float4 w3 = *(const float4*)&fw[(j4 + 3) * FEAT + os * 4];
        #pragma unroll
        for (int r = 0; r < 8; ++r) {
            float4 a = *(const float4*)&Atile[(rg * 8 + r) * FEAT + os * 4];
            acc[r][0] += a.x * w0.x + a.y * w0.y + a.z * w0.z + a.w * w0.w;
            acc[r][1] += a.x * w1.x + a.y * w1.y + a.z * w1.z + a.w * w1.w;
            acc[r][2] += a.x * w2.x + a.y * w2.y + a.z * w2.z + a.w * w2.w;
            acc[r][3] += a.x * w3.x + a.y * w3.y + a.z * w3.z + a.w * w3.w;
        }
    }

    float4 b4 = *(const float4*)&fb[j4];
    #pragma unroll
    for (int r = 0; r < 8; ++r) {
        int gr = row0 + rg * 8 + r;
        if (gr < N_NODES) {
            float4 v = make_float4(acc[r][0] + b4.x, acc[r][1] + b4.y,
                                   acc[r][2] + b4.z, acc[r][3] + b4.w);
            *(float4*)&out[gr * FEAT + j4] = v;
        }
    }
}

// ---------------------------------------------------------------------------
extern "C" void kernel_launch(void* const* d_in, const int* in_sizes, int n_in,
                              void* d_out, int out_size, void* d_ws, size_t ws_size,
                              hipStream_t stream) {
    const float* node_state = (const float*)d_in[0];
    const float* edge_w     = (const float*)d_in[1];
    const float* weight     = (const float*)d_in[2];
    const float* bias       = (const float*)d_in[3];
    const float* final_w    = (const float*)d_in[4];
    const float* final_b    = (const float*)d_in[5];
    const int*   src        = (const int*)d_in[6];
    const int*   dst        = (const int*)d_in[7];
    float* out = (float*)d_out;

    // Workspace layout (bytes):
    //   agg: [C][N][F] f32   = 102,400,000
    //   h:   [N][F]    f32   =  25,600,000
    //   Wt:  [C][O][F] f32   =     262,144
    char* ws = (char*)d_ws;
    float* agg = (float*)ws;                          // 102.4 MB
    float* h   = (float*)(ws + 102400000);            //  25.6 MB
    float* wt  = (float*)(ws + 128000000);            //   0.25 MB

    hipMemsetAsync(agg, 0, (size_t)CH * NF * sizeof(float), stream);

    pack_w_kernel<<<(FEAT * FEAT * CH + 255) / 256, 256, 0, stream>>>(weight, wt);

    scatter_kernel<<<N_EDGES / 2, 256, 0, stream>>>(node_state, edge_w, src, dst, agg);

    int nblk = (N_NODES + 63) / 64;
    gemm1_kernel<<<nblk, 256, 0, stream>>>(agg, wt, bias, h);
    gemm2_kernel<<<nblk, 256, 0, stream>>>(h, final_w, final_b, out);
}

// Round 2
// 874.215 us; speedup vs baseline: 1.9408x; 1.9408x over previous
//
#include <hip/hip_runtime.h>
#include <hip/hip_bf16.h>

#define N_NODES 50000
#define N_EDGES 800000
#define FEAT 128
#define CH 4
#define TM 32   // nodes per block in fused kernel

// ---------------------------------------------------------------------------
// Pack weight [F][O][C] -> Wt [C][O][F] (contiguous float4 along F).
// ---------------------------------------------------------------------------
__global__ void pack_w_kernel(const float* __restrict__ w, float* __restrict__ wt) {
    int idx = blockIdx.x * blockDim.x + threadIdx.x;  // over 128*128*4
    if (idx >= FEAT * FEAT * CH) return;
    int c = idx & 3;
    int o = (idx >> 2) & 127;
    int f = idx >> 9;
    wt[c * (FEAT * FEAT) + o * FEAT + f] = w[idx];
}

// ---------------------------------------------------------------------------
// Counting sort by dst: histogram -> exclusive scan -> scatter.
// ---------------------------------------------------------------------------
__global__ __launch_bounds__(256) void hist_kernel(const int* __restrict__ dst,
                                                   int* __restrict__ deg) {
    int e = blockIdx.x * 256 + threadIdx.x;
    if (e < N_EDGES) atomicAdd(&deg[dst[e]], 1);
}

__global__ __launch_bounds__(1024) void scan_kernel(const int* __restrict__ deg,
                                                    int* __restrict__ offs) {
    // single block, 1024 threads, wave-shuffle scan over 50000 elems
    __shared__ int wsum[16];
    __shared__ int carry_s;
    const int t = threadIdx.x;
    const int lane = t & 63, wid = t >> 6;
    if (t == 0) carry_s = 0;
    __syncthreads();
    for (int base = 0; base < N_NODES; base += 1024) {
        int v = (base + t < N_NODES) ? deg[base + t] : 0;
        int incl = v;
        #pragma unroll
        for (int off = 1; off < 64; off <<= 1) {
            int u = __shfl_up(incl, off, 64);
            if (lane >= off) incl += u;
        }
        if (lane == 63) wsum[wid] = incl;
        __syncthreads();
        if (wid == 0 && lane < 16) {
            int s = wsum[lane];
            int sc = s;
            #pragma unroll
            for (int off = 1; off < 16; off <<= 1) {
                int u = __shfl_up(sc, off, 64);
                if (lane >= off) sc += u;
            }
            wsum[lane] = sc - s;  // exclusive wave-sum prefix
        }
        __syncthreads();
        int carry = carry_s;
        int excl = carry + wsum[wid] + incl - v;
        if (base + t < N_NODES) offs[base + t] = excl;
        __syncthreads();  // everyone read carry_s before update
        if (t == 1023) carry_s = excl + v;
        __syncthreads();
    }
    if (threadIdx.x == 0) offs[N_NODES] = carry_s;
}

__global__ __launch_bounds__(256) void sortscatter_kernel(
        const int* __restrict__ src, const int* __restrict__ dst,
        const float* __restrict__ ew, int* __restrict__ cur,
        int* __restrict__ sorted_src, float4* __restrict__ sorted_w) {
    int e = blockIdx.x * 256 + threadIdx.x;
    if (e >= N_EDGES) return;
    int d = dst[e];
    int pos = atomicAdd(&cur[d], 1);
    sorted_src[pos] = src[e];
    sorted_w[pos] = ((const float4*)ew)[e];
}

// ---------------------------------------------------------------------------
// Fused: per 32-node tile, aggregate into LDS (4ch x 32 x 128 = 64KB), then
// GEMM1 (+bias,relu,channel-sum) from LDS, then GEMM2 from LDS. agg and h
// never touch global memory.
// ---------------------------------------------------------------------------
__global__ __launch_bounds__(256) void fused_kernel(
        const float* __restrict__ node_state,
        const int* __restrict__ offs,
        const int* __restrict__ sorted_src,
        const float4* __restrict__ sorted_w,
        const float* __restrict__ wt,
        const float* __restrict__ bias,
        const float* __restrict__ fw,
        const float* __restrict__ fb,
        float* __restrict__ out) {
    __shared__ float aggLDS[CH][TM][FEAT];  // 64 KB
    const int row0 = blockIdx.x * TM;
    const int t = threadIdx.x;
    const int lane = t & 63;
    const int wid = t >> 6;  // 0..3

    // ---- phase 1: each wave aggregates 8 nodes; lane covers feats 2l,2l+1 ----
    const float2* ns2 = (const float2*)node_state;
    for (int r = 0; r < 8; ++r) {
        const int row = wid * 8 + r;
        const int gn = row0 + row;
        float2 a0 = {0.f, 0.f}, a1 = {0.f, 0.f}, a2 = {0.f, 0.f}, a3 = {0.f, 0.f};
        if (gn < N_NODES) {
            const int beg = offs[gn], end = offs[gn + 1];
            #pragma unroll 2
            for (int e = beg; e < end; ++e) {
                const int s = sorted_src[e];       // wave-uniform -> broadcast
                const float4 w4 = sorted_w[e];
                const float2 x = ns2[s * 64 + lane];
                a0.x += x.x * w4.x; a0.y += x.y * w4.x;
                a1.x += x.x * w4.y; a1.y += x.y * w4.y;
                a2.x += x.x * w4.z; a2.y += x.y * w4.z;
                a3.x += x.x * w4.w; a3.y += x.y * w4.w;
            }
        }
        *(float2*)&aggLDS[0][row][lane * 2] = a0;
        *(float2*)&aggLDS[1][row][lane * 2] = a1;
        *(float2*)&aggLDS[2][row][lane * 2] = a2;
        *(float2*)&aggLDS[3][row][lane * 2] = a3;
    }
    __syncthreads();

    // ---- phase 2: h = sum_c relu(agg_c @ Wt_c + b_c), tile in registers ----
    const int o4 = (t & 31) * 4;
    const int rg = t >> 5;  // 0..7 -> rows rg*4 .. rg*4+3
    float hacc[4][4];
    #pragma unroll
    for (int r = 0; r < 4; ++r)
        #pragma unroll
        for (int i = 0; i < 4; ++i) hacc[r][i] = 0.f;

    for (int c = 0; c < CH; ++c) {
        float acc[4][4];
        #pragma unroll
        for (int r = 0; r < 4; ++r)
            #pragma unroll
            for (int i = 0; i < 4; ++i) acc[r][i] = 0.f;
        const float* wc = wt + c * (FEAT * FEAT);
        for (int fs = 0; fs < FEAT / 4; ++fs) {
            const float4 w0 = *(const float4*)&wc[(o4 + 0) * FEAT + fs * 4];
            const float4 w1 = *(const float4*)&wc[(o4 + 1) * FEAT + fs * 4];
            const float4 w2 = *(const float4*)&wc[(o4 + 2) * FEAT + fs * 4];
            const float4 w3 = *(const float4*)&wc[(o4 + 3) * FEAT + fs * 4];
            #pragma unroll
            for (int r = 0; r < 4; ++r) {
                const float4 a = *(const float4*)&aggLDS[c][rg * 4 + r][fs * 4];
                acc[r][0] += a.x * w0.x + a.y * w0.y + a.z * w0.z + a.w * w0.w;
                acc[r][1] += a.x * w1.x + a.y * w1.y + a.z * w1.z + a.w * w1.w;
                acc[r][2] += a.x * w2.x + a.y * w2.y + a.z * w2.z + a.w * w2.w;
                acc[r][3] += a.x * w3.x + a.y * w3.y + a.z * w3.z + a.w * w3.w;
            }
        }
        #pragma unroll
        for (int i = 0; i < 4; ++i) {
            const float b = bias[(o4 + i) * CH + c];
            #pragma unroll
            for (int r = 0; r < 4; ++r)
                hacc[r][i] += fmaxf(acc[r][i] + b, 0.f);
        }
    }
    __syncthreads();  // all aggLDS reads done before reuse

    // ---- phase 3: h tile -> LDS (reuse aggLDS[0]) ----
    float (*hLDS)[FEAT] = (float (*)[FEAT]) & aggLDS[0][0][0];
    #pragma unroll
    for (int r = 0; r < 4; ++r)
        *(float4*)&hLDS[rg * 4 + r][o4] =
            make_float4(hacc[r][0], hacc[r][1], hacc[r][2], hacc[r][3]);
    __syncthreads();

    // ---- phase 4: out = h @ fw^T + fb ----
    float acc2[4][4];
    #pragma unroll
    for (int r = 0; r < 4; ++r)
        #pragma unroll
        for (int i = 0; i < 4; ++i) acc2[r][i] = 0.f;
    for (int os = 0; os < FEAT / 4; ++os) {
        const float4 w0 = *(const float4*)&fw[(o4 + 0) * FEAT + os * 4];
        const float4 w1 = *(const float4*)&fw[(o4 + 1) * FEAT + os * 4];
        const float4 w2 = *(const float4*)&fw[(o4 + 2) * FEAT + os * 4];
        const float4 w3 = *(const float4*)&fw[(o4 + 3) * FEAT + os * 4];
        #pragma unroll
        for (int r = 0; r < 4; ++r) {
            const float4 a = *(const float4*)&hLDS[rg * 4 + r][os * 4];
            acc2[r][0] += a.x * w0.x + a.y * w0.y + a.z * w0.z + a.w * w0.w;
            acc2[r][1] += a.x * w1.x + a.y * w1.y + a.z * w1.z + a.w * w1.w;
            acc2[r][2] += a.x * w2.x + a.y * w2.y + a.z * w2.z + a.w * w2.w;
            acc2[r][3] += a.x * w3.x + a.y * w3.y + a.z * w3.z + a.w * w3.w;
        }
    }
    const float4 b4 = *(const float4*)&fb[o4];
    #pragma unroll
    for (int r = 0; r < 4; ++r) {
        const int gr = row0 + rg * 4 + r;
        if (gr < N_NODES) {
            *(float4*)&out[gr * FEAT + o4] =
                make_float4(acc2[r][0] + b4.x, acc2[r][1] + b4.y,
                            acc2[r][2] + b4.z, acc2[r][3] + b4.w);
        }
    }
}

// ---------------------------------------------------------------------------
extern "C" void kernel_launch(void* const* d_in, const int* in_sizes, int n_in,
                              void* d_out, int out_size, void* d_ws, size_t ws_size,
                              hipStream_t stream) {
    const float* node_state = (const float*)d_in[0];
    const float* edge_w     = (const float*)d_in[1];
    const float* weight     = (const float*)d_in[2];
    const float* bias       = (const float*)d_in[3];
    const float* final_w    = (const float*)d_in[4];
    const float* final_b    = (const float*)d_in[5];
    const int*   src        = (const int*)d_in[6];
    const int*   dst        = (const int*)d_in[7];
    float* out = (float*)d_out;

    // Workspace layout (16B-aligned chunks):
    char* ws = (char*)d_ws;
    int*    deg        = (int*)(ws + 0);          // 200,000 B
    int*    offs       = (int*)(ws + 200064);     // 200,004 B (50001)
    int*    cur        = (int*)(ws + 400128);     // 200,000 B
    int*    sorted_src = (int*)(ws + 600192);     // 3.2 MB
    float4* sorted_w   = (float4*)(ws + 3800192); // 12.8 MB
    float*  wt         = (float*)(ws + 16600192); // 262,144 B
    // total ~16.9 MB

    hipMemsetAsync(deg, 0, N_NODES * sizeof(int), stream);

    pack_w_kernel<<<(FEAT * FEAT * CH + 255) / 256, 256, 0, stream>>>(weight, wt);

    hist_kernel<<<(N_EDGES + 255) / 256, 256, 0, stream>>>(dst, deg);
    scan_kernel<<<1, 1024, 0, stream>>>(deg, offs);
    hipMemcpyAsync(cur, offs, N_NODES * sizeof(int), hipMemcpyDeviceToDevice, stream);
    sortscatter_kernel<<<(N_EDGES + 255) / 256, 256, 0, stream>>>(
        src, dst, edge_w, cur, sorted_src, sorted_w);

    fused_kernel<<<(N_NODES + TM - 1) / TM, 256, 0, stream>>>(
        node_state, offs, sorted_src, sorted_w, wt, bias, final_w, final_b, out);
}

// Round 4
// 471.425 us; speedup vs baseline: 3.5990x; 1.8544x over previous
//
#include <hip/hip_runtime.h>
#include <hip/hip_bf16.h>

#define N_NODES 50000
#define N_EDGES 800000
#define FEAT 128
#define CH 4
#define TM 16          // nodes per fused block (50000 = 16*3125, no tail)

// ---------------------------------------------------------------------------
// Pack weight [F][O][C] -> wt4 [C][KC=32][O=128][4]  (K-major, float4 over k%4)
// ---------------------------------------------------------------------------
__global__ __launch_bounds__(256) void pack_w4_kernel(const float* __restrict__ w,
                                                      float* __restrict__ wt4) {
    int idx = blockIdx.x * 256 + threadIdx.x;  // over 128*128*4 = 65536
    if (idx >= FEAT * FEAT * CH) return;
    int j  = idx & 3;
    int o  = (idx >> 2) & 127;
    int kc = (idx >> 9) & 31;
    int c  = idx >> 14;
    int f  = kc * 4 + j;
    wt4[idx] = w[(f * FEAT + o) * CH + c];
}

// final_w [J][O] -> fwt4 [KC=32][J=128][4] where k = o-dim
__global__ __launch_bounds__(256) void pack_fw4_kernel(const float* __restrict__ fw,
                                                       float* __restrict__ fwt4) {
    int idx = blockIdx.x * 256 + threadIdx.x;  // over 128*128 = 16384
    if (idx >= FEAT * FEAT) return;
    int j   = idx & 3;
    int col = (idx >> 2) & 127;
    int kc  = idx >> 9;
    fwt4[idx] = fw[col * FEAT + kc * 4 + j];
}

// ---------------------------------------------------------------------------
// Counting sort by dst: histogram -> scan (R2-proven monolithic) -> scatter.
// ---------------------------------------------------------------------------
__global__ __launch_bounds__(256) void hist_kernel(const int* __restrict__ dst,
                                                   int* __restrict__ deg) {
    int e = blockIdx.x * 256 + threadIdx.x;
    if (e < N_EDGES) atomicAdd(&deg[dst[e]], 1);
}

__global__ __launch_bounds__(1024) void scan_kernel(const int* __restrict__ deg,
                                                    int* __restrict__ offs) {
    // single block, 1024 threads, wave-shuffle scan over 50000 elems
    __shared__ int wsum[16];
    __shared__ int carry_s;
    const int t = threadIdx.x;
    const int lane = t & 63, wid = t >> 6;
    if (t == 0) carry_s = 0;
    __syncthreads();
    for (int base = 0; base < N_NODES; base += 1024) {
        int v = (base + t < N_NODES) ? deg[base + t] : 0;
        int incl = v;
        #pragma unroll
        for (int off = 1; off < 64; off <<= 1) {
            int u = __shfl_up(incl, off, 64);
            if (lane >= off) incl += u;
        }
        if (lane == 63) wsum[wid] = incl;
        __syncthreads();
        if (wid == 0 && lane < 16) {
            int s = wsum[lane];
            int sc = s;
            #pragma unroll
            for (int off = 1; off < 16; off <<= 1) {
                int u = __shfl_up(sc, off, 64);
                if (lane >= off) sc += u;
            }
            wsum[lane] = sc - s;  // exclusive wave-sum prefix
        }
        __syncthreads();
        int carry = carry_s;
        int excl = carry + wsum[wid] + incl - v;
        if (base + t < N_NODES) offs[base + t] = excl;
        __syncthreads();  // everyone read carry_s before update
        if (t == 1023) carry_s = excl + v;
        __syncthreads();
    }
    if (threadIdx.x == 0) offs[N_NODES] = carry_s;
}

__global__ __launch_bounds__(256) void sortscatter_kernel(
        const int* __restrict__ src, const int* __restrict__ dst,
        const float* __restrict__ ew, int* __restrict__ cur,
        int* __restrict__ sorted_src, float4* __restrict__ sorted_w) {
    int e = blockIdx.x * 256 + threadIdx.x;
    if (e >= N_EDGES) return;
    int d = dst[e];
    int pos = atomicAdd(&cur[d], 1);
    sorted_src[pos] = src[e];
    sorted_w[pos] = ((const float4*)ew)[e];
}

// ---------------------------------------------------------------------------
// Fused: per 16-node tile: CSR aggregate into LDS (4ch x 16 x 128 = 32 KB,
// 4-deep pipelined gathers), then GEMM1(+bias,relu,ch-sum) and GEMM2 with
// K-major weights (coalesced loads) and wave-uniform LDS A-broadcasts.
// ---------------------------------------------------------------------------
#define EDGE_FMA(xx, ww)                                  \
    a0.x += xx.x * ww.x; a0.y += xx.y * ww.x;             \
    a1.x += xx.x * ww.y; a1.y += xx.y * ww.y;             \
    a2.x += xx.x * ww.z; a2.y += xx.y * ww.z;             \
    a3.x += xx.x * ww.w; a3.y += xx.y * ww.w;

__global__ __launch_bounds__(256) void fused_kernel(
        const float* __restrict__ node_state,
        const int* __restrict__ offs,
        const int* __restrict__ sorted_src,
        const float4* __restrict__ sorted_w,
        const float4* __restrict__ wt4,
        const float* __restrict__ bias,
        const float4* __restrict__ fwt4,
        const float* __restrict__ fb,
        float* __restrict__ out) {
    __shared__ float aggLDS[CH][TM][FEAT];  // 32 KB
    const int t = threadIdx.x;
    const int lane = t & 63;
    const int wid = t >> 6;  // 0..3
    const int row0 = blockIdx.x * TM;
    const float2* ns2 = (const float2*)node_state;

    // ---- phase 1: wave wid aggregates nodes wid*4 .. wid*4+3 ----
    for (int r = 0; r < 4; ++r) {
        const int row = wid * 4 + r;
        const int gn = row0 + row;
        float2 a0{0.f, 0.f}, a1{0.f, 0.f}, a2{0.f, 0.f}, a3{0.f, 0.f};
        {
            int e = offs[gn];
            const int end = offs[gn + 1];
            for (; e + 4 <= end; e += 4) {  // 4-deep pipeline: 4 gathers in flight
                const int s0 = sorted_src[e + 0];
                const int s1 = sorted_src[e + 1];
                const int s2 = sorted_src[e + 2];
                const int s3 = sorted_src[e + 3];
                const float4 w0 = sorted_w[e + 0];
                const float4 w1 = sorted_w[e + 1];
                const float4 w2 = sorted_w[e + 2];
                const float4 w3 = sorted_w[e + 3];
                const float2 x0 = ns2[s0 * 64 + lane];
                const float2 x1 = ns2[s1 * 64 + lane];
                const float2 x2 = ns2[s2 * 64 + lane];
                const float2 x3 = ns2[s3 * 64 + lane];
                EDGE_FMA(x0, w0)
                EDGE_FMA(x1, w1)
                EDGE_FMA(x2, w2)
                EDGE_FMA(x3, w3)
            }
            for (; e < end; ++e) {
                const int s0 = sorted_src[e];
                const float4 w0 = sorted_w[e];
                const float2 x0 = ns2[s0 * 64 + lane];
                EDGE_FMA(x0, w0)
            }
        }
        *(float2*)&aggLDS[0][row][lane * 2] = a0;
        *(float2*)&aggLDS[1][row][lane * 2] = a1;
        *(float2*)&aggLDS[2][row][lane * 2] = a2;
        *(float2*)&aggLDS[3][row][lane * 2] = a3;
    }
    __syncthreads();

    // ---- phase 2: h = sum_c relu(agg_c @ W_c + b_c) ----
    // thread -> (col = t&127, rows rg8..rg8+7); A from LDS (wave-uniform
    // broadcast), W coalesced float4 from K-major pack.
    const int col = t & 127;
    const int rg8 = (t >> 7) * 8;  // 0 or 8; wave-uniform
    float hacc[8];
    #pragma unroll
    for (int r = 0; r < 8; ++r) hacc[r] = 0.f;

    for (int c = 0; c < CH; ++c) {
        float acc[8];
        #pragma unroll
        for (int r = 0; r < 8; ++r) acc[r] = 0.f;
        for (int kc = 0; kc < 32; ++kc) {
            const float4 wv = wt4[(c * 32 + kc) * FEAT + col];
            #pragma unroll
            for (int r = 0; r < 8; ++r) {
                const float4 a = *(const float4*)&aggLDS[c][rg8 + r][kc * 4];
                acc[r] += a.x * wv.x + a.y * wv.y + a.z * wv.z + a.w * wv.w;
            }
        }
        const float b = bias[col * CH + c];
        #pragma unroll
        for (int r = 0; r < 8; ++r) hacc[r] += fmaxf(acc[r] + b, 0.f);
    }
    __syncthreads();  // all aggLDS reads done before reuse

    // ---- phase 3: h tile -> LDS (reuse aggLDS[0]) ----
    float (*hLDS)[FEAT] = (float (*)[FEAT]) & aggLDS[0][0][0];
    #pragma unroll
    for (int r = 0; r < 8; ++r) hLDS[rg8 + r][col] = hacc[r];
    __syncthreads();

    // ---- phase 4: out = h @ fw^T + fb ----
    float acc2[8];
    #pragma unroll
    for (int r = 0; r < 8; ++r) acc2[r] = 0.f;
    for (int kc = 0; kc < 32; ++kc) {
        const float4 wv = fwt4[kc * FEAT + col];
        #pragma unroll
        for (int r = 0; r < 8; ++r) {
            const float4 a = *(const float4*)&hLDS[rg8 + r][kc * 4];
            acc2[r] += a.x * wv.x + a.y * wv.y + a.z * wv.z + a.w * wv.w;
        }
    }
    const float b2 = fb[col];
    #pragma unroll
    for (int r = 0; r < 8; ++r) {
        const int gr = row0 + rg8 + r;
        out[gr * FEAT + col] = acc2[r] + b2;  // 50000 % 16 == 0, no guard needed
    }
}

// ---------------------------------------------------------------------------
extern "C" void kernel_launch(void* const* d_in, const int* in_sizes, int n_in,
                              void* d_out, int out_size, void* d_ws, size_t ws_size,
                              hipStream_t stream) {
    const float* node_state = (const float*)d_in[0];
    const float* edge_w     = (const float*)d_in[1];
    const float* weight     = (const float*)d_in[2];
    const float* bias       = (const float*)d_in[3];
    const float* final_w    = (const float*)d_in[4];
    const float* final_b    = (const float*)d_in[5];
    const int*   src        = (const int*)d_in[6];
    const int*   dst        = (const int*)d_in[7];
    float* out = (float*)d_out;

    // Workspace layout (16B-aligned chunks):
    char* ws = (char*)d_ws;
    int*    deg        = (int*)(ws + 0);          // 200,000 B
    int*    offs       = (int*)(ws + 200064);     // 200,004 B (50001 ints)
    int*    cur        = (int*)(ws + 400128);     // 200,000 B
    int*    sorted_src = (int*)(ws + 600448);     // 3.2 MB
    float4* sorted_w   = (float4*)(ws + 3800448); // 12.8 MB
    float*  wt4        = (float*)(ws + 16600448); // 262,144 B
    float*  fwt4       = (float*)(ws + 16862592); // 65,536 B
    // total ~16.93 MB

    hipMemsetAsync(deg, 0, N_NODES * sizeof(int), stream);

    pack_w4_kernel<<<(FEAT * FEAT * CH + 255) / 256, 256, 0, stream>>>(weight, wt4);
    pack_fw4_kernel<<<(FEAT * FEAT + 255) / 256, 256, 0, stream>>>(final_w, fwt4);

    hist_kernel<<<(N_EDGES + 255) / 256, 256, 0, stream>>>(dst, deg);
    scan_kernel<<<1, 1024, 0, stream>>>(deg, offs);
    hipMemcpyAsync(cur, offs, N_NODES * sizeof(int), hipMemcpyDeviceToDevice, stream);
    sortscatter_kernel<<<(N_EDGES + 255) / 256, 256, 0, stream>>>(
        src, dst, edge_w, cur, sorted_src, sorted_w);

    fused_kernel<<<N_NODES / TM, 256, 0, stream>>>(
        node_state, offs, sorted_src, sorted_w,
        (const float4*)wt4, bias, (const float4*)fwt4, final_b, out);
}

// Round 5
// 323.499 us; speedup vs baseline: 5.2446x; 1.4573x over previous
//
#include <hip/hip_runtime.h>
#include <hip/hip_bf16.h>

#define N_NODES 50000
#define N_EDGES 800000
#define FEAT 128
#define CH 4
#define TM 16          // nodes per fused block (50000 = 16*3125, no tail)

typedef __attribute__((ext_vector_type(8))) __bf16 bf16x8;
typedef __attribute__((ext_vector_type(4))) float  f32x4;

static __device__ __forceinline__ unsigned short f2bf(float x) {
    union { float f; unsigned u; } v; v.f = x;
    unsigned r = v.u + 0x7fffu + ((v.u >> 16) & 1u);  // round-to-nearest-even
    return (unsigned short)(r >> 16);
}
static __device__ __forceinline__ unsigned packbf2(float a, float b) {
    return (unsigned)f2bf(a) | ((unsigned)f2bf(b) << 16);
}

// ---------------------------------------------------------------------------
// Pack weight [F][O][C] into GEMM1 B-fragments (bf16):
//   wfrag[((c*4 + kt)*8 + ct)*64 + lane] = 8 bf16 of
//     W_c[k = kt*32 + (lane>>4)*8 + j][o = ct*16 + (lane&15)], j=0..7
// (B-frag layout for mfma_f32_16x16x32_bf16: col = lane&15, k-group = lane>>4)
// ---------------------------------------------------------------------------
__global__ __launch_bounds__(256) void pack_wfrag_kernel(const float* __restrict__ w,
                                                         uint4* __restrict__ wf) {
    int idx = blockIdx.x * 256 + threadIdx.x;  // over 4*4*8*64 = 8192
    if (idx >= CH * 4 * 8 * 64) return;
    int lane = idx & 63;
    int ct   = (idx >> 6) & 7;
    int kt   = (idx >> 9) & 3;
    int c    = idx >> 11;
    int o    = ct * 16 + (lane & 15);
    int f0   = kt * 32 + (lane >> 4) * 8;
    unsigned r[4];
    #pragma unroll
    for (int p = 0; p < 4; ++p) {
        float lo = w[((f0 + 2 * p + 0) * FEAT + o) * CH + c];
        float hi = w[((f0 + 2 * p + 1) * FEAT + o) * CH + c];
        r[p] = packbf2(lo, hi);
    }
    wf[idx] = make_uint4(r[0], r[1], r[2], r[3]);
}

// final_w [J][O] into GEMM2 B-fragments (k = o dim):
//   ffrag[(kt*8 + ct)*64 + lane] = 8 bf16 of fw[j = ct*16+(lane&15)][o = kt*32+(lane>>4)*8+j']
__global__ __launch_bounds__(256) void pack_fwfrag_kernel(const float* __restrict__ fw,
                                                          uint4* __restrict__ ff) {
    int idx = blockIdx.x * 256 + threadIdx.x;  // over 4*8*64 = 2048
    if (idx >= 4 * 8 * 64) return;
    int lane = idx & 63;
    int ct   = (idx >> 6) & 7;
    int kt   = idx >> 9;
    int j    = ct * 16 + (lane & 15);
    int o0   = kt * 32 + (lane >> 4) * 8;
    unsigned r[4];
    #pragma unroll
    for (int p = 0; p < 4; ++p)
        r[p] = packbf2(fw[j * FEAT + o0 + 2 * p], fw[j * FEAT + o0 + 2 * p + 1]);
    ff[idx] = make_uint4(r[0], r[1], r[2], r[3]);
}

// ---------------------------------------------------------------------------
// Counting sort by dst: histogram -> scan (R2/R4-proven monolithic) -> scatter.
// ---------------------------------------------------------------------------
__global__ __launch_bounds__(256) void hist_kernel(const int* __restrict__ dst,
                                                   int* __restrict__ deg) {
    int e = blockIdx.x * 256 + threadIdx.x;
    if (e < N_EDGES) atomicAdd(&deg[dst[e]], 1);
}

__global__ __launch_bounds__(1024) void scan_kernel(const int* __restrict__ deg,
                                                    int* __restrict__ offs) {
    __shared__ int wsum[16];
    __shared__ int carry_s;
    const int t = threadIdx.x;
    const int lane = t & 63, wid = t >> 6;
    if (t == 0) carry_s = 0;
    __syncthreads();
    for (int base = 0; base < N_NODES; base += 1024) {
        int v = (base + t < N_NODES) ? deg[base + t] : 0;
        int incl = v;
        #pragma unroll
        for (int off = 1; off < 64; off <<= 1) {
            int u = __shfl_up(incl, off, 64);
            if (lane >= off) incl += u;
        }
        if (lane == 63) wsum[wid] = incl;
        __syncthreads();
        if (wid == 0 && lane < 16) {
            int s = wsum[lane];
            int sc = s;
            #pragma unroll
            for (int off = 1; off < 16; off <<= 1) {
                int u = __shfl_up(sc, off, 64);
                if (lane >= off) sc += u;
            }
            wsum[lane] = sc - s;  // exclusive wave-sum prefix
        }
        __syncthreads();
        int carry = carry_s;
        int excl = carry + wsum[wid] + incl - v;
        if (base + t < N_NODES) offs[base + t] = excl;
        __syncthreads();  // everyone read carry_s before update
        if (t == 1023) carry_s = excl + v;
        __syncthreads();
    }
    if (threadIdx.x == 0) offs[N_NODES] = carry_s;
}

__global__ __launch_bounds__(256) void sortscatter_kernel(
        const int* __restrict__ src, const int* __restrict__ dst,
        const float* __restrict__ ew, int* __restrict__ cur,
        int* __restrict__ sorted_src, float4* __restrict__ sorted_w) {
    int e = blockIdx.x * 256 + threadIdx.x;
    if (e >= N_EDGES) return;
    int d = dst[e];
    int pos = atomicAdd(&cur[d], 1);
    sorted_src[pos] = src[e];
    sorted_w[pos] = ((const float4*)ew)[e];
}

// ---------------------------------------------------------------------------
// Fused: per 16-node tile:
//   phase 1: CSR aggregate (f32) -> bf16 into XOR-swizzled LDS
//   phase 2: GEMM1 via mfma_f32_16x16x32_bf16 (+bias,relu,channel-sum)
//   phase 3: h tile -> bf16 LDS (same swizzle family)
//   phase 4: GEMM2 via MFMA, + final bias, f32 out
// B-operands come prepacked from global (coalesced 16B/lane, L2-resident).
// Swizzle: physical element = logical element ^ ((row&7)<<3)  [bf16 units]
//          == physical word  = logical word    ^ ((row&7)<<2)  [32-bit units]
// ---------------------------------------------------------------------------
#define EDGE_FMA(xx, ww)                                  \
    a0.x += xx.x * ww.x; a0.y += xx.y * ww.x;             \
    a1.x += xx.x * ww.y; a1.y += xx.y * ww.y;             \
    a2.x += xx.x * ww.z; a2.y += xx.y * ww.z;             \
    a3.x += xx.x * ww.w; a3.y += xx.y * ww.w;

__global__ __launch_bounds__(256) void fused_kernel(
        const float* __restrict__ node_state,
        const int* __restrict__ offs,
        const int* __restrict__ sorted_src,
        const float4* __restrict__ sorted_w,
        const uint4* __restrict__ wfrag,
        const float* __restrict__ bias,
        const uint4* __restrict__ fwfrag,
        const float* __restrict__ fb,
        float* __restrict__ out) {
    __shared__ unsigned aggU[CH][TM][64];        // bf16 pairs, 16 KB
    __shared__ unsigned short hS[TM][FEAT];      // bf16, 4 KB
    const int t = threadIdx.x;
    const int lane = t & 63;
    const int wid = t >> 6;  // 0..3
    const int row0 = blockIdx.x * TM;
    const float2* ns2 = (const float2*)node_state;

    // ---- phase 1: wave wid aggregates nodes wid*4 .. wid*4+3 ----
    for (int r = 0; r < 4; ++r) {
        const int row = wid * 4 + r;
        const int gn = row0 + row;
        float2 a0{0.f, 0.f}, a1{0.f, 0.f}, a2{0.f, 0.f}, a3{0.f, 0.f};
        {
            int e = offs[gn];
            const int end = offs[gn + 1];
            for (; e + 4 <= end; e += 4) {  // 4-deep pipeline: 4 gathers in flight
                const int s0 = sorted_src[e + 0];
                const int s1 = sorted_src[e + 1];
                const int s2 = sorted_src[e + 2];
                const int s3 = sorted_src[e + 3];
                const float4 w0 = sorted_w[e + 0];
                const float4 w1 = sorted_w[e + 1];
                const float4 w2 = sorted_w[e + 2];
                const float4 w3 = sorted_w[e + 3];
                const float2 x0 = ns2[s0 * 64 + lane];
                const float2 x1 = ns2[s1 * 64 + lane];
                const float2 x2 = ns2[s2 * 64 + lane];
                const float2 x3 = ns2[s3 * 64 + lane];
                EDGE_FMA(x0, w0)
                EDGE_FMA(x1, w1)
                EDGE_FMA(x2, w2)
                EDGE_FMA(x3, w3)
            }
            for (; e < end; ++e) {
                const int s0 = sorted_src[e];
                const float4 w0 = sorted_w[e];
                const float2 x0 = ns2[s0 * 64 + lane];
                EDGE_FMA(x0, w0)
            }
        }
        const int sw = lane ^ ((row & 7) << 2);  // swizzled word index
        aggU[0][row][sw] = packbf2(a0.x, a0.y);
        aggU[1][row][sw] = packbf2(a1.x, a1.y);
        aggU[2][row][sw] = packbf2(a2.x, a2.y);
        aggU[3][row][sw] = packbf2(a3.x, a3.y);
    }
    __syncthreads();

    // ---- phase 2: GEMM1 h = sum_c relu(agg_c @ W_c + b_c) via MFMA ----
    // A-frag: row = lane&15, k = (lane>>4)*8 + j (8 contiguous bf16)
    const int arow = lane & 15;
    const int kg4  = (lane >> 4) << 2;   // k-group in words
    const int asw  = (arow & 7) << 2;
    const int ct0  = wid * 2;            // this wave's two 16-col tiles
    const int colA = ct0 * 16 + arow;
    const int colB = colA + 16;

    f32x4 hacc0 = {0.f, 0.f, 0.f, 0.f}, hacc1 = {0.f, 0.f, 0.f, 0.f};
    #pragma unroll
    for (int c = 0; c < CH; ++c) {
        f32x4 acc0 = {0.f, 0.f, 0.f, 0.f}, acc1 = {0.f, 0.f, 0.f, 0.f};
        #pragma unroll
        for (int kt = 0; kt < 4; ++kt) {
            const uint4 au = *(const uint4*)&aggU[c][arow][(kt * 16 + kg4) ^ asw];
            const bf16x8 a  = __builtin_bit_cast(bf16x8, au);
            const bf16x8 b0 = __builtin_bit_cast(bf16x8, wfrag[((c * 4 + kt) * 8 + ct0) * 64 + lane]);
            const bf16x8 b1 = __builtin_bit_cast(bf16x8, wfrag[((c * 4 + kt) * 8 + ct0 + 1) * 64 + lane]);
            acc0 = __builtin_amdgcn_mfma_f32_16x16x32_bf16(a, b0, acc0, 0, 0, 0);
            acc1 = __builtin_amdgcn_mfma_f32_16x16x32_bf16(a, b1, acc1, 0, 0, 0);
        }
        const float bb0 = bias[colA * CH + c];
        const float bb1 = bias[colB * CH + c];
        #pragma unroll
        for (int q = 0; q < 4; ++q) {
            hacc0[q] += fmaxf(acc0[q] + bb0, 0.f);
            hacc1[q] += fmaxf(acc1[q] + bb1, 0.f);
        }
    }

    // ---- phase 3: h tile -> LDS bf16 (C/D layout: col=lane&15(+16ct), row=(lane>>4)*4+q) ----
    const int rrow0 = (lane >> 4) << 2;
    #pragma unroll
    for (int q = 0; q < 4; ++q) {
        const int row = rrow0 + q;
        const int s8 = (row & 7) << 3;
        hS[row][colA ^ s8] = f2bf(hacc0[q]);
        hS[row][colB ^ s8] = f2bf(hacc1[q]);
    }
    __syncthreads();

    // ---- phase 4: GEMM2 out = h @ fw^T + fb via MFMA ----
    f32x4 o0 = {0.f, 0.f, 0.f, 0.f}, o1 = {0.f, 0.f, 0.f, 0.f};
    const int asw8 = (arow & 7) << 3;
    #pragma unroll
    for (int kt = 0; kt < 4; ++kt) {
        const uint4 hu = *(const uint4*)&hS[arow][(kt * 32 + (kg4 << 1)) ^ asw8];
        const bf16x8 a  = __builtin_bit_cast(bf16x8, hu);
        const bf16x8 b0 = __builtin_bit_cast(bf16x8, fwfrag[(kt * 8 + ct0) * 64 + lane]);
        const bf16x8 b1 = __builtin_bit_cast(bf16x8, fwfrag[(kt * 8 + ct0 + 1) * 64 + lane]);
        o0 = __builtin_amdgcn_mfma_f32_16x16x32_bf16(a, b0, o0, 0, 0, 0);
        o1 = __builtin_amdgcn_mfma_f32_16x16x32_bf16(a, b1, o1, 0, 0, 0);
    }
    const float fb0 = fb[colA];
    const float fb1 = fb[colB];
    #pragma unroll
    for (int q = 0; q < 4; ++q) {
        const int gr = row0 + rrow0 + q;
        out[gr * FEAT + colA] = o0[q] + fb0;
        out[gr * FEAT + colB] = o1[q] + fb1;
    }
}

// ---------------------------------------------------------------------------
extern "C" void kernel_launch(void* const* d_in, const int* in_sizes, int n_in,
                              void* d_out, int out_size, void* d_ws, size_t ws_size,
                              hipStream_t stream) {
    const float* node_state = (const float*)d_in[0];
    const float* edge_w     = (const float*)d_in[1];
    const float* weight     = (const float*)d_in[2];
    const float* bias       = (const float*)d_in[3];
    const float* final_w    = (const float*)d_in[4];
    const float* final_b    = (const float*)d_in[5];
    const int*   src        = (const int*)d_in[6];
    const int*   dst        = (const int*)d_in[7];
    float* out = (float*)d_out;

    // Workspace layout (16B-aligned chunks):
    char* ws = (char*)d_ws;
    int*    deg        = (int*)(ws + 0);           // 200,000 B
    int*    offs       = (int*)(ws + 200064);      // 200,004 B (50001 ints)
    int*    cur        = (int*)(ws + 400128);      // 200,000 B
    int*    sorted_src = (int*)(ws + 600448);      // 3.2 MB
    float4* sorted_w   = (float4*)(ws + 3800448);  // 12.8 MB
    uint4*  wfrag      = (uint4*)(ws + 16600448);  // 131,072 B
    uint4*  fwfrag     = (uint4*)(ws + 16731520);  // 32,768 B
    // total ~16.77 MB

    hipMemsetAsync(deg, 0, N_NODES * sizeof(int), stream);

    pack_wfrag_kernel<<<(CH * 4 * 8 * 64 + 255) / 256, 256, 0, stream>>>(weight, wfrag);
    pack_fwfrag_kernel<<<(4 * 8 * 64 + 255) / 256, 256, 0, stream>>>(final_w, fwfrag);

    hist_kernel<<<(N_EDGES + 255) / 256, 256, 0, stream>>>(dst, deg);
    scan_kernel<<<1, 1024, 0, stream>>>(deg, offs);
    hipMemcpyAsync(cur, offs, N_NODES * sizeof(int), hipMemcpyDeviceToDevice, stream);
    sortscatter_kernel<<<(N_EDGES + 255) / 256, 256, 0, stream>>>(
        src, dst, edge_w, cur, sorted_src, sorted_w);

    fused_kernel<<<N_NODES / TM, 256, 0, stream>>>(
        node_state, offs, sorted_src, sorted_w,
        wfrag, bias, fwfrag, final_b, out);
}